// Round 19
// baseline (756.018 us; speedup 1.0000x reference)
//
#include <hip/hip_runtime.h>
#include <hip/hip_bf16.h>
#include <hip/hip_fp16.h>
#include <math.h>

#define BB 8
#define TT 4096
#define CC 512
#define BT (BB*TT)
#define KD 256
#define VD 512
#define NSUB 64
#define SUB 64

using bf16 = __hip_bfloat16;
using f16 = _Float16;
typedef __attribute__((ext_vector_type(2))) float f32x2;
typedef __attribute__((ext_vector_type(4))) float f32x4;
typedef __attribute__((ext_vector_type(8))) short s16x8;
typedef __attribute__((ext_vector_type(8))) unsigned short u16x8;
typedef const __attribute__((address_space(1))) unsigned int gu32;
typedef __attribute__((address_space(3))) unsigned int lu32;

static __device__ __forceinline__ float bf2f(bf16 x){ return __bfloat162float(x); }
static __device__ __forceinline__ bf16 f2bf(float x){ return __float2bfloat16(x); }
static __device__ __forceinline__ float bfbits(unsigned short u){
  union { unsigned int i; float f; } x; x.i = ((unsigned int)u)<<16; return x.f;
}
static __device__ __forceinline__ unsigned short f2bfbits(float f){
  union { bf16 b; unsigned short u; } x; x.b = f2bf(f); return x.u;
}
static __device__ __forceinline__ float h2f(unsigned short u){
  f16 h; __builtin_memcpy(&h,&u,2); return (float)h;
}
static __device__ __forceinline__ void gload16(const void* g, void* l){
  __builtin_amdgcn_global_load_lds((gu32*)g, (lu32*)l, 16, 0, 0);
}

// ---------------- workspace arena (bytes); Mseg lives in d_out ----------------
#define MiB 1048576ull
static constexpr size_t OFF_H1   = 0;           // bf16 BT*C (32)  ; p3 out GATED ; FFN RF
static constexpr size_t OFF_XX   = 32*MiB;      // bf16 BT*256 (16); dead by scan
static constexpr size_t OFF_DSEG = 32*MiB;      // f32 2048*64 (0.5) alias XX
static constexpr size_t OFF_HM   = 48*MiB;      // bf16 BT*C (32) = xm, then hm0
static constexpr size_t OFF_R    = 80*MiB;      // bf16 BT*256 (16); FFN KIN (spans R+K)
static constexpr size_t OFF_K    = 96*MiB;      // bf16 BT*256 (16)
static constexpr size_t OFF_V    = 112*MiB;     // bf16 BT*512 (32); FFN RIN
static constexpr size_t OFF_WD   = 144*MiB;     // f16 BT*256 (16) ew; build: hm4 (32); FFN KF low
static constexpr size_t OFF_G    = 176*MiB;     // build: hm3 ; then g (32); FFN KF high
static constexpr size_t OFF_W1T  = 208*MiB;     // bf16 BT*64 (4)
static constexpr size_t WT_X1  = 212*MiB;            // 512x256 bf16
static constexpr size_t WT_R   = WT_X1  + 262144;
static constexpr size_t WT_K   = WT_R   + 262144;
static constexpr size_t WT_V   = WT_K   + 262144;
static constexpr size_t WT_G   = WT_V   + 524288;
static constexpr size_t WT_W1  = WT_G   + 524288;
static constexpr size_t WT_W2  = WT_W1  + 65536;
static constexpr size_t WT_O   = WT_W2  + 32768;
static constexpr size_t WT_KEY = WT_O   + 524288;
static constexpr size_t WT_REC = WT_KEY + 1048576;
static constexpr size_t WT_VAL = WT_REC + 524288;
static constexpr size_t WT_X2T = WT_VAL + 1048576;   // bf16 [5][512][32]
static constexpr size_t WS_NEED = WT_X2T + 163840;

// ---------------- tiled transposed weight convert (coalesced both sides) ----------------
__global__ __launch_bounds__(256) void wconv_t2(const float* s0, const float* s1, const float* s2,
        const float* s3, const float* s4, const float* s5, const float* s6, const float* s7,
        const float* s8, const float* s9, const float* s10, char* ws){
  struct E{int K,N,Npad; size_t off;};
  const E tab[11] = {
    {512,160,256,WT_X1},{512,256,256,WT_R},{512,256,256,WT_K},{512,512,512,WT_V},
    {512,512,512,WT_G},{512,64,64,WT_W1},{64,256,256,WT_W2},{512,512,512,WT_O},
    {512,1024,1024,WT_KEY},{512,512,512,WT_REC},{1024,512,512,WT_VAL}};
  const float* srcs[11] = {s0,s1,s2,s3,s4,s5,s6,s7,s8,s9,s10};
  int blk = blockIdx.x, i = 0, acc = 0;
  #pragma unroll 1
  for (; i<11; i++){ int nt = (tab[i].K>>6)*(tab[i].Npad>>6); if (blk < acc+nt) break; acc += nt; }
  int local = blk - acc;
  int K = tab[i].K, N = tab[i].N;
  int ntn = tab[i].Npad>>6;
  int k0 = (local/ntn)*64, n0 = (local%ntn)*64;
  const float* src = srcs[i];
  bf16* dst = (bf16*)(ws + tab[i].off);
  __shared__ float T[64][65];
  int t = threadIdx.x;
  #pragma unroll
  for (int e=0;e<16;e++){
    int idx = t + e*256; int r = idx>>6, c = idx&63;
    int n = n0 + c;
    T[r][c] = (n < N) ? src[(size_t)(k0+r)*N + n] : 0.f;
  }
  __syncthreads();
  #pragma unroll
  for (int e=0;e<16;e++){
    int idx = t + e*256; int r = idx>>6, c = idx&63;
    dst[(size_t)(n0+r)*K + k0 + c] = f2bf(T[c][r]);
  }
}

// ---------------- W_x2 -> bf16 [5][512][32] transposed (tiny) ----------------
__global__ void wconv_x2(const float* __restrict__ src, bf16* __restrict__ dst){
  int idx = blockIdx.x*256 + threadIdx.x;   // 81920 total
  int i = idx >> 14;
  int rem = idx & 16383;
  int c = rem >> 5, r = rem & 31;
  dst[idx] = f2bf(src[((size_t)i*32 + r)*512 + c]);
}

// ---------------- fused LN + token-shift lerp (attn): writes h1 AND xm ----------------
__global__ __launch_bounds__(256) void ln_xm(const float* __restrict__ x, const float* __restrict__ w,
        const float* __restrict__ b, const float* __restrict__ mu_x,
        bf16* __restrict__ h1, bf16* __restrict__ xm){
  int bt = blockIdx.x;
  bool hasp = (bt & (TT-1)) != 0;
  const float* row = x + (size_t)bt*CC;
  int t = threadIdx.x;
  float a0 = row[t], a1 = row[t+256];
  float p0 = 0.f, p1 = 0.f;
  if (hasp){ p0 = row[t-512]; p1 = row[t-256]; }
  float s = a0+a1, ss = a0*a0+a1*a1, sp = p0+p1, ssp = p0*p0+p1*p1;
  for (int off=32; off; off>>=1){
    s += __shfl_down(s,off,64); ss += __shfl_down(ss,off,64);
    sp += __shfl_down(sp,off,64); ssp += __shfl_down(ssp,off,64);
  }
  __shared__ float ps[4], pss[4], psp[4], pssp[4];
  int wv = t>>6, ln = t&63;
  if (ln==0){ ps[wv]=s; pss[wv]=ss; psp[wv]=sp; pssp[wv]=ssp; }
  __syncthreads();
  if (t==0){
    float S=ps[0]+ps[1]+ps[2]+ps[3], SS=pss[0]+pss[1]+pss[2]+pss[3];
    float SP=psp[0]+psp[1]+psp[2]+psp[3], SSP=pssp[0]+pssp[1]+pssp[2]+pssp[3];
    float mu = S/CC; float var = SS/CC - mu*mu;
    float mup = SP/CC; float varp = SSP/CC - mup*mup;
    ps[0]=mu; pss[0]=rsqrtf(var+1e-5f);
    psp[0]=mup; pssp[0]=rsqrtf(varp+1e-5f);
  }
  __syncthreads();
  float mu = ps[0], inv = pss[0], mup = psp[0], invp = pssp[0];
  float h0 = (a0-mu)*inv*w[t]+b[t];
  float h1v = (a1-mu)*inv*w[t+256]+b[t+256];
  float q0 = hasp ? (p0-mup)*invp*w[t]+b[t] : 0.f;
  float q1 = hasp ? (p1-mup)*invp*w[t+256]+b[t+256] : 0.f;
  size_t base = (size_t)bt*CC;
  h1[base+t]     = f2bf(h0);
  h1[base+t+256] = f2bf(h1v);
  xm[base+t]     = f2bf(h0 + (q0-h0)*mu_x[t]);
  xm[base+t+256] = f2bf(h1v + (q1-h1v)*mu_x[t+256]);
}

// ---------------- fused LN + FFN lerp: writes kin AND rin (hn eliminated) ----------------
__global__ __launch_bounds__(256) void ln_ffn(const float* __restrict__ x, const float* __restrict__ w,
        const float* __restrict__ b, const float* __restrict__ mu_k, const float* __restrict__ mu_r,
        bf16* __restrict__ kin, bf16* __restrict__ rin){
  int bt = blockIdx.x;
  bool hasp = (bt & (TT-1)) != 0;
  const float* row = x + (size_t)bt*CC;
  int t = threadIdx.x;
  float a0 = row[t], a1 = row[t+256];
  float p0 = 0.f, p1 = 0.f;
  if (hasp){ p0 = row[t-512]; p1 = row[t-256]; }
  float s = a0+a1, ss = a0*a0+a1*a1, sp = p0+p1, ssp = p0*p0+p1*p1;
  for (int off=32; off; off>>=1){
    s += __shfl_down(s,off,64); ss += __shfl_down(ss,off,64);
    sp += __shfl_down(sp,off,64); ssp += __shfl_down(ssp,off,64);
  }
  __shared__ float ps[4], pss[4], psp[4], pssp[4];
  int wv = t>>6, ln = t&63;
  if (ln==0){ ps[wv]=s; pss[wv]=ss; psp[wv]=sp; pssp[wv]=ssp; }
  __syncthreads();
  if (t==0){
    float S=ps[0]+ps[1]+ps[2]+ps[3], SS=pss[0]+pss[1]+pss[2]+pss[3];
    float SP=psp[0]+psp[1]+psp[2]+psp[3], SSP=pssp[0]+pssp[1]+pssp[2]+pssp[3];
    float mu = S/CC; float var = SS/CC - mu*mu;
    float mup = SP/CC; float varp = SSP/CC - mup*mup;
    ps[0]=mu; pss[0]=rsqrtf(var+1e-5f);
    psp[0]=mup; pssp[0]=rsqrtf(varp+1e-5f);
  }
  __syncthreads();
  float mu = ps[0], inv = pss[0], mup = psp[0], invp = pssp[0];
  float h0 = (a0-mu)*inv*w[t]+b[t];
  float h1v = (a1-mu)*inv*w[t+256]+b[t+256];
  float q0 = hasp ? (p0-mup)*invp*w[t]+b[t] : 0.f;
  float q1 = hasp ? (p1-mup)*invp*w[t+256]+b[t+256] : 0.f;
  float d0 = q0-h0, d1 = q1-h1v;
  size_t base = (size_t)bt*CC;
  kin[base+t]     = f2bf(h0 + d0*mu_k[t]);
  kin[base+t+256] = f2bf(h1v + d1*mu_k[t+256]);
  rin[base+t]     = f2bf(h0 + d0*mu_r[t]);
  rin[base+t+256] = f2bf(h1v + d1*mu_r[t+256]);
}

// ---------------- MFMA-fused 5-way lerp-mix build ----------------
__global__ __launch_bounds__(256) void hm5_mfma(const bf16* __restrict__ h, const bf16* __restrict__ xx,
      const bf16* __restrict__ wx2t, const float* __restrict__ x_bias,
      bf16* __restrict__ hm0, bf16* __restrict__ hm1, bf16* __restrict__ hm2,
      bf16* __restrict__ hm3, bf16* __restrict__ hm4){
  __shared__ bf16 xxl[128][168];
  int bt0 = blockIdx.x*128;
  int c0 = blockIdx.y*128;
  int tid = threadIdx.x;
  #pragma unroll
  for (int p=0;p<10;p++){
    int idx = p*256 + tid;
    int row = idx/20, q = idx - row*20;
    *(uint4*)&xxl[row][q*8] = *(const uint4*)&xx[((size_t)(bt0+row))*256 + q*8];
  }
  __syncthreads();
  int wv = tid>>6, ln = tid&63;
  int wr = wv>>1, wc = wv&1;
  int ks = (ln>>4)*8;
  int l15 = ln&15;
  bf16* const outs[5] = {hm0,hm1,hm2,hm3,hm4};
  #pragma unroll
  for (int i=0;i<5;i++){
    s16x8 bq[4];
    #pragma unroll
    for (int ni=0;ni<4;ni++)
      bq[ni] = *(const s16x8*)&xxl[wc*64 + ni*16 + l15][i*32 + ks];
    f32x4 acc[4][4];
    #pragma unroll
    for (int mi=0;mi<4;mi++){
      int chb = c0 + wr*64 + mi*16 + (ln>>4)*4;
      float4 bia = *(const float4*)&x_bias[i*CC + chb];
      #pragma unroll
      for (int ni=0;ni<4;ni++){ f32x4 a = {bia.x,bia.y,bia.z,bia.w}; acc[mi][ni] = a; }
    }
    #pragma unroll
    for (int mi=0;mi<4;mi++){
      s16x8 aw = *(const s16x8*)&wx2t[((size_t)i*512 + c0 + wr*64 + mi*16 + l15)*32 + ks];
      #pragma unroll
      for (int ni=0;ni<4;ni++)
        acc[mi][ni] = __builtin_amdgcn_mfma_f32_16x16x32_bf16(aw, bq[ni], acc[mi][ni], 0,0,0);
    }
    bf16* o = outs[i];
    #pragma unroll
    for (int mi=0;mi<4;mi++){
      int ch = c0 + wr*64 + mi*16 + (ln>>4)*4;
      #pragma unroll
      for (int ni=0;ni<4;ni++){
        int tok = bt0 + wc*64 + ni*16 + l15;
        size_t base = (size_t)tok*CC + ch;
        ushort4 hv4 = *(const ushort4*)&((const unsigned short*)h)[base];
        ushort4 hp4;
        if (tok & (TT-1)) hp4 = *(const ushort4*)&((const unsigned short*)h)[base - CC];
        else { hp4.x=0; hp4.y=0; hp4.z=0; hp4.w=0; }
        ushort4 o4;
        float hv, hp, mus;
        hv = bfbits(hv4.x); hp = bfbits(hp4.x); mus = acc[mi][ni][0]; o4.x = f2bfbits(hv + (hp-hv)*mus);
        hv = bfbits(hv4.y); hp = bfbits(hp4.y); mus = acc[mi][ni][1]; o4.y = f2bfbits(hv + (hp-hv)*mus);
        hv = bfbits(hv4.z); hp = bfbits(hp4.z); mus = acc[mi][ni][2]; o4.z = f2bfbits(hv + (hp-hv)*mus);
        hv = bfbits(hv4.w); hp = bfbits(hp4.w); mus = acc[mi][ni][3]; o4.w = f2bfbits(hv + (hp-hv)*mus);
        *(ushort4*)&((unsigned short*)o)[base] = o4;
      }
    }
  }
}

// ---------------- epilogue modes ----------------
enum {EP_BF16, EP_TANH_BF16, EP_NEGEXP_F16, EP_RES_F32, EP_RELU2_BF16, EP_SIG_BF16, EP_FINAL_F32};

// ---------------- 128x128 MFMA GEMM, BK=64, XOR-swizzled LDS (linear dest + pre-swz src) ----
template<int MODE>
__global__ __launch_bounds__(256) void gemm128(
    const bf16* __restrict__ A, const bf16* __restrict__ Bt, void* __restrict__ Out,
    int N, int K, const float* __restrict__ auxf, const bf16* __restrict__ auxb)
{
  __shared__ bf16 Al[128][64];
  __shared__ bf16 Bl[128][64];
  int tid = threadIdx.x;
  int nbk = N>>7;
  int q8 = gridDim.x>>3;
  int o = (blockIdx.x & 7)*q8 + (blockIdx.x>>3);
  int nb = o % nbk, mb = o / nbk;
  int m0 = mb*128, n0 = nb*128;
  int wv = tid>>6, ln = tid&63;
  int wr = wv>>1, wc = wv&1;
  f32x4 acc[4][4];
  #pragma unroll
  for (int i=0;i<4;i++) for (int j=0;j<4;j++){ f32x4 z={0.f,0.f,0.f,0.f}; acc[i][j]=z; }
  int r0 = tid>>3;
  int sl = (tid&7) ^ (r0&7);
  int l15 = ln&15, lswz = l15&7;
  const int nkt = K>>6;
  for (int kt=0; kt<nkt; kt++){
    const bf16* ga = A  + (size_t)(m0+r0)*K + kt*64 + sl*8;
    const bf16* gb = Bt + (size_t)(n0+r0)*K + kt*64 + sl*8;
    #pragma unroll
    for (int j=0;j<4;j++){
      gload16(ga + (size_t)(j*32)*K, (char*)&Al[0][0] + (tid + j*256)*16);
      gload16(gb + (size_t)(j*32)*K, (char*)&Bl[0][0] + (tid + j*256)*16);
    }
    __syncthreads();
    #pragma unroll
    for (int kh=0; kh<2; kh++){
      int slot = (kh*4 + (ln>>4)) ^ lswz;
      s16x8 af[4], bq[4];
      #pragma unroll
      for (int i=0;i<4;i++){
        int ra = wr*64 + i*16 + l15;
        int rb2 = wc*64 + i*16 + l15;
        af[i] = *(const s16x8*)((const char*)&Al[0][0] + ra*128 + slot*16);
        bq[i] = *(const s16x8*)((const char*)&Bl[0][0] + rb2*128 + slot*16);
      }
      #pragma unroll
      for (int mi=0;mi<4;mi++)
        #pragma unroll
        for (int ni=0;ni<4;ni++)
          acc[mi][ni] = __builtin_amdgcn_mfma_f32_16x16x32_bf16(af[mi], bq[ni], acc[mi][ni], 0,0,0);
    }
    __syncthreads();
  }
  #pragma unroll
  for (int mi=0;mi<4;mi++)
    #pragma unroll
    for (int ni=0;ni<4;ni++){
      int col = n0 + wc*64 + ni*16 + (ln&15);
      int rb  = m0 + wr*64 + mi*16 + (ln>>4)*4;
      #pragma unroll
      for (int j=0;j<4;j++){
        size_t idx = (size_t)(rb+j)*N + col;
        float val = acc[mi][ni][j];
        if constexpr(MODE==EP_BF16)           ((bf16*)Out)[idx] = f2bf(val);
        else if constexpr(MODE==EP_TANH_BF16) ((bf16*)Out)[idx] = f2bf(tanhf(val));
        else if constexpr(MODE==EP_RES_F32)   ((float*)Out)[idx] = auxf[idx] + val;
        else if constexpr(MODE==EP_RELU2_BF16){ float m = fmaxf(val,0.f); ((bf16*)Out)[idx] = f2bf(m*m); }
        else if constexpr(MODE==EP_SIG_BF16)  ((bf16*)Out)[idx] = f2bf(1.f/(1.f+expf(-val)));
        else if constexpr(MODE==EP_FINAL_F32) ((float*)Out)[idx] = auxf[idx] + bf2f(auxb[idx])*val;
      }
    }
}

// ---------------- 128x64-tile GEMM, BK=64, same swizzle (N=256 outputs) -------------
template<int MODE>
__global__ __launch_bounds__(256) void gemm12864(
    const bf16* __restrict__ A, const bf16* __restrict__ Bt, void* __restrict__ Out,
    int N, int K)
{
  __shared__ bf16 Al[128][64];
  __shared__ bf16 Bl[64][64];
  int tid = threadIdx.x;
  int nbk = N>>6;
  int q8 = gridDim.x>>3;
  int o = (blockIdx.x & 7)*q8 + (blockIdx.x>>3);
  int nb = o % nbk, mb = o / nbk;
  int m0 = mb*128, n0 = nb*64;
  int wv = tid>>6, ln = tid&63;
  int wr = wv>>1, wc = wv&1;
  f32x4 acc[4][2];
  #pragma unroll
  for (int i=0;i<4;i++) for (int j=0;j<2;j++){ f32x4 z={0.f,0.f,0.f,0.f}; acc[i][j]=z; }
  int r0 = tid>>3;
  int sl = (tid&7) ^ (r0&7);
  int l15 = ln&15, lswz = l15&7;
  const int nkt = K>>6;
  for (int kt=0; kt<nkt; kt++){
    const bf16* ga = A  + (size_t)(m0+r0)*K + kt*64 + sl*8;
    const bf16* gb = Bt + (size_t)(n0+r0)*K + kt*64 + sl*8;
    #pragma unroll
    for (int j=0;j<4;j++)
      gload16(ga + (size_t)(j*32)*K, (char*)&Al[0][0] + (tid + j*256)*16);
    #pragma unroll
    for (int j=0;j<2;j++)
      gload16(gb + (size_t)(j*32)*K, (char*)&Bl[0][0] + (tid + j*256)*16);
    __syncthreads();
    #pragma unroll
    for (int kh=0; kh<2; kh++){
      int slot = (kh*4 + (ln>>4)) ^ lswz;
      s16x8 af[4], bq[2];
      #pragma unroll
      for (int i=0;i<4;i++){
        int ra = wr*64 + i*16 + l15;
        af[i] = *(const s16x8*)((const char*)&Al[0][0] + ra*128 + slot*16);
      }
      #pragma unroll
      for (int i=0;i<2;i++){
        int rb2 = wc*32 + i*16 + l15;
        bq[i] = *(const s16x8*)((const char*)&Bl[0][0] + rb2*128 + slot*16);
      }
      #pragma unroll
      for (int mi=0;mi<4;mi++)
        #pragma unroll
        for (int ni=0;ni<2;ni++)
          acc[mi][ni] = __builtin_amdgcn_mfma_f32_16x16x32_bf16(af[mi], bq[ni], acc[mi][ni], 0,0,0);
    }
    __syncthreads();
  }
  #pragma unroll
  for (int mi=0;mi<4;mi++)
    #pragma unroll
    for (int ni=0;ni<2;ni++){
      int col = n0 + wc*32 + ni*16 + (ln&15);
      int rb  = m0 + wr*64 + mi*16 + (ln>>4)*4;
      #pragma unroll
      for (int j=0;j<4;j++){
        size_t idx = (size_t)(rb+j)*N + col;
        float val = acc[mi][ni][j];
        if constexpr(MODE==EP_BF16)           ((bf16*)Out)[idx] = f2bf(val);
        else if constexpr(MODE==EP_TANH_BF16) ((bf16*)Out)[idx] = f2bf(tanhf(val));
      }
    }
}

// ---------------- small-N GEMM (used for W1 N=64 and W2 K=64) -------------
template<int MODE>
__global__ __launch_bounds__(256) void gemm_bf16(
    const bf16* __restrict__ A, const bf16* __restrict__ Bt, void* __restrict__ Out,
    int N, int K, const float* __restrict__ bias)
{
  __shared__ bf16 Al[128][40];
  __shared__ bf16 Bl[64][40];
  int tid = threadIdx.x;
  int m0 = blockIdx.x*128, n0 = blockIdx.y*64;
  int wv = tid>>6, ln = tid&63;
  f32x4 acc[2][4];
  #pragma unroll
  for(int f=0;f<2;f++) for(int c=0;c<4;c++){ f32x4 z = {0.f,0.f,0.f,0.f}; acc[f][c]=z; }
  const int nkt = K>>5;
  for (int kt=0; kt<nkt; kt++){
    __syncthreads();
    {
      int c0 = tid, c1 = tid+256;
      int r = c0>>2, ko=(c0&3)*8;
      *(uint4*)&Al[r][ko] = *(const uint4*)&A[(size_t)(m0+r)*K + kt*32 + ko];
      r = c1>>2; ko=(c1&3)*8;
      *(uint4*)&Al[r][ko] = *(const uint4*)&A[(size_t)(m0+r)*K + kt*32 + ko];
      r = tid>>2; ko=(tid&3)*8;
      *(uint4*)&Bl[r][ko] = *(const uint4*)&Bt[(size_t)(n0+r)*K + kt*32 + ko];
    }
    __syncthreads();
    int ks = (ln>>4)*8;
    s16x8 af0 = *(const s16x8*)&Al[wv*32 + (ln&15)][ks];
    s16x8 af1 = *(const s16x8*)&Al[wv*32 + 16 + (ln&15)][ks];
    #pragma unroll
    for (int c=0;c<4;c++){
      s16x8 bfr = *(const s16x8*)&Bl[c*16 + (ln&15)][ks];
      acc[0][c] = __builtin_amdgcn_mfma_f32_16x16x32_bf16(af0, bfr, acc[0][c], 0,0,0);
      acc[1][c] = __builtin_amdgcn_mfma_f32_16x16x32_bf16(af1, bfr, acc[1][c], 0,0,0);
    }
  }
  #pragma unroll
  for (int f=0; f<2; f++) for (int c=0;c<4;c++){
    int col = n0 + c*16 + (ln&15);
    int rbase = m0 + wv*32 + f*16 + (ln>>4)*4;
    #pragma unroll
    for (int j=0;j<4;j++){
      size_t idx = (size_t)(rbase+j)*N + col;
      float val = acc[f][c][j];
      if constexpr(MODE==EP_TANH_BF16)      ((bf16*)Out)[idx] = f2bf(tanhf(val));
      else if constexpr(MODE==EP_NEGEXP_F16){
        float w = fmaxf(-expf(val + bias[col]), -20.f);
        ((f16*)Out)[idx] = (f16)expf(w);
      }
    }
  }
}

// ---------------- WKV6 segment scan (64-token chunks, NSUB=64) ----------------
// P1: 256 threads; thread = (k-lane, v-quarter). ew/k staged coalescedly into LDS per 16-token tile.
__global__ __launch_bounds__(256) void wkv_p1(const bf16* __restrict__ kbuf, const bf16* __restrict__ vbuf,
      const f16* __restrict__ ewb, bf16* __restrict__ Mseg, float* __restrict__ Dseg){
  int bhs = blockIdx.x; int bh = bhs>>6, sub = bhs&63;
  int b = bh>>2, h = bh&3;
  int tid = threadIdx.x, ln = tid&63, vq = tid>>6;
  __shared__ float vtile[16][132];
  __shared__ float ew16[16][66];
  __shared__ float qk16[16][66];
  int t0 = sub*SUB;
  float dacc = 1.f;
  f32x2 S2[16];
  #pragma unroll
  for (int p=0;p<16;p++){ f32x2 z={0.f,0.f}; S2[p]=z; }
  #pragma unroll 1
  for (int tile=0; tile<4; tile++){
    int tb = t0 + tile*16;
    __syncthreads();
    {
      int t = tid>>4, c = (tid&15)*8;
      u16x8 a8 = *(const u16x8*)&((const unsigned short*)vbuf)[((size_t)b*TT + tb + t)*VD + h*128 + c];
      float4 lo, hi;
      lo.x=bfbits(a8[0]); lo.y=bfbits(a8[1]); lo.z=bfbits(a8[2]); lo.w=bfbits(a8[3]);
      hi.x=bfbits(a8[4]); hi.y=bfbits(a8[5]); hi.z=bfbits(a8[6]); hi.w=bfbits(a8[7]);
      *(float4*)&vtile[t][c]   = lo;
      *(float4*)&vtile[t][c+4] = hi;
    }
    #pragma unroll
    for (int j=0;j<2;j++){
      int idx = j*512 + tid*2;
      int t = idx>>6, c = idx&63;
      size_t gi = ((size_t)b*TT + tb + t)*KD + h*64 + c;
      ushort2 e2 = *(const ushort2*)&((const unsigned short*)ewb)[gi];
      ushort2 k2 = *(const ushort2*)&((const unsigned short*)kbuf)[gi];
      ew16[t][c] = h2f(e2.x);   ew16[t][c+1] = h2f(e2.y);
      qk16[t][c] = bfbits(k2.x); qk16[t][c+1] = bfbits(k2.y);
    }
    __syncthreads();
    #pragma unroll 2
    for (int tt=0;tt<16;tt++){
      float e = ew16[tt][ln];
      float qv = qk16[tt][ln];
      dacc *= e;
      f32x2 e2v = {e,e}, q2 = {qv,qv};
      #pragma unroll
      for (int vg=0;vg<8;vg++){
        f32x4 vvv = *(const f32x4*)&vtile[tt][vq*32 + vg*4];
        f32x2 vA = {vvv[0], vvv[1]}, vB = {vvv[2], vvv[3]};
        S2[vg*2]   = e2v*S2[vg*2]   + q2*vA;
        S2[vg*2+1] = e2v*S2[vg*2+1] + q2*vB;
      }
    }
  }
  unsigned short* M = (unsigned short*)Mseg + (size_t)bhs*8192 + (size_t)ln*128 + vq*32;
  #pragma unroll
  for (int vg=0; vg<8; vg++){
    ushort4 s4;
    s4.x = f2bfbits(S2[vg*2][0]);   s4.y = f2bfbits(S2[vg*2][1]);
    s4.z = f2bfbits(S2[vg*2+1][0]); s4.w = f2bfbits(S2[vg*2+1][1]);
    *(ushort4*)&M[vg*4] = s4;
  }
  if (vq==0) Dseg[(size_t)bhs*64 + ln] = dacc;
}

// P2: sequential combine across sub-chunks, IN-PLACE bf16 (Mseg becomes Sstart)
__global__ __launch_bounds__(256) void wkv_p2(bf16* __restrict__ MS, const float* __restrict__ Dseg){
  int idx = blockIdx.x*256 + threadIdx.x;
  int bh = idx>>13; int k = (idx>>7)&63; int v = idx&127;
  bf16* p = MS + (size_t)bh*NSUB*8192 + k*128 + v;
  const float* d = Dseg + (size_t)bh*NSUB*64 + k;
  float S = 0.f;
  float m = bf2f(p[0]); float D = d[0];
  #pragma unroll 1
  for (int seg=0; seg<NSUB; seg++){
    float mN=0.f, DN=0.f;
    if (seg < NSUB-1){ mN = bf2f(p[(size_t)(seg+1)*8192]); DN = d[(seg+1)*64]; }
    p[(size_t)seg*8192] = f2bf(S);
    S = D*S + m;
    m = mN; D = DN;
  }
}

// P3: 256 threads; thread = (k-QUARTER, 2 v-channels). State S2[16] = 16 k x f32x2(2 channels).
// otp partials stored as bf16 (halves LDS -> 8 blocks/CU); accumulation stays f32.
__global__ __launch_bounds__(256) void wkv_p3(const bf16* __restrict__ rbuf, const bf16* __restrict__ kbuf,
     const bf16* __restrict__ vbuf, const f16* __restrict__ ewb, const bf16* __restrict__ Sstart,
     const float* __restrict__ uu, const bf16* __restrict__ gg,
     const float* __restrict__ gn_w, const float* __restrict__ gn_b, bf16* __restrict__ gated){
  int bhs = blockIdx.x; int bh = bhs>>6, sub = bhs&63;
  int b = bh>>2, h = bh&3;
  int tid = threadIdx.x;
  __shared__ float ew[8][68], qk[8][68], rr[8][68], bu[8];
  __shared__ unsigned short vtb[8][128];
  __shared__ __align__(16) unsigned short otpb[4][8][132];
  int v0 = tid&63, kq = tid>>6, kbase = kq*16;
  int tq = tid>>5, c2 = (tid&31)*2, cq4 = (tid&31)*4;
  float2 u2 = *(const float2*)&uu[h*64 + c2];
  f32x2 S2[16];   // S2[p] = { S[kbase+p][v0], S[kbase+p][v0+64] }
  const unsigned short* Sst = (const unsigned short*)Sstart + (size_t)bhs*8192;
  #pragma unroll
  for (int p=0;p<16;p++){
    f32x2 s = { bfbits(Sst[(kbase+p)*128 + v0]), bfbits(Sst[(kbase+p)*128 + v0 + 64]) };
    S2[p] = s;
  }
  int t0 = sub*SUB;
  ushort2 nE, nK, nR; ushort4 nV;
  auto loadt = [&](int tile){
    int tb = t0 + tile*8;
    size_t gi = ((size_t)b*TT + tb + tq)*KD + h*64 + c2;
    nE = *(const ushort2*)&((const unsigned short*)ewb)[gi];
    nK = *(const ushort2*)&((const unsigned short*)kbuf)[gi];
    nR = *(const ushort2*)&((const unsigned short*)rbuf)[gi];
    nV = *(const ushort4*)&((const unsigned short*)vbuf)[((size_t)b*TT + tb + tq)*VD + h*128 + cq4];
  };
  loadt(0);
  #pragma unroll 1
  for (int tile=0; tile<8; tile++){
    int tb = t0 + tile*8;
    {
      ew[tq][c2] = h2f(nE.x); ew[tq][c2+1] = h2f(nE.y);
      float q0=bfbits(nK.x), q1=bfbits(nK.y);
      float rv0=bfbits(nR.x), rv1=bfbits(nR.y);
      qk[tq][c2]=q0; qk[tq][c2+1]=q1;
      rr[tq][c2]=rv0; rr[tq][c2+1]=rv1;
      float part = rv0*q0*u2.x + rv1*q1*u2.y;
      part += __shfl_xor(part,1,64); part += __shfl_xor(part,2,64);
      part += __shfl_xor(part,4,64); part += __shfl_xor(part,8,64);
      part += __shfl_xor(part,16,64);
      if ((tid&31)==0) bu[tq] = part;
      *(ushort4*)&vtb[tq][cq4] = nV;
    }
    __syncthreads();
    if (tile < 7) loadt(tile+1);
    #pragma unroll 1
    for (int t=0;t<8;t++){
      f32x2 vl2 = { bfbits(vtb[t][v0]), bfbits(vtb[t][v0+64]) };
      f32x2 o2 = {0.f, 0.f};
      #pragma unroll
      for (int g=0;g<4;g++){
        f32x4 e4 = *(const f32x4*)&ew[t][kbase + g*4];
        f32x4 q4 = *(const f32x4*)&qk[t][kbase + g*4];
        f32x4 r4 = *(const f32x4*)&rr[t][kbase + g*4];
        int p = g*4;
        f32x2 e0={e4[0],e4[0]}, q0={q4[0],q4[0]}, r0={r4[0],r4[0]};
        f32x2 e1={e4[1],e4[1]}, q1={q4[1],q4[1]}, r1={r4[1],r4[1]};
        f32x2 e2={e4[2],e4[2]}, q2={q4[2],q4[2]}, r2={r4[2],r4[2]};
        f32x2 e3={e4[3],e4[3]}, q3={q4[3],q4[3]}, r3={r4[3],r4[3]};
        o2 += r0*S2[p+0]; S2[p+0] = e0*S2[p+0] + q0*vl2;
        o2 += r1*S2[p+1]; S2[p+1] = e1*S2[p+1] + q1*vl2;
        o2 += r2*S2[p+2]; S2[p+2] = e2*S2[p+2] + q2*vl2;
        o2 += r3*S2[p+3]; S2[p+3] = e3*S2[p+3] + q3*vl2;
      }
      if (kq==0){ float bb = bu[t]; o2[0] += bb*vl2[0]; o2[1] += bb*vl2[1]; }
      otpb[kq][t][v0]      = f2bfbits(o2[0]);
      otpb[kq][t][v0 + 64] = f2bfbits(o2[1]);
    }
    __syncthreads();
    {
      ushort4 aA = *(const ushort4*)&otpb[0][tq][cq4];
      ushort4 aB = *(const ushort4*)&otpb[1][tq][cq4];
      ushort4 aC = *(const ushort4*)&otpb[2][tq][cq4];
      ushort4 aD = *(const ushort4*)&otpb[3][tq][cq4];
      float o4[4];
      o4[0] = bfbits(aA.x)+bfbits(aB.x)+bfbits(aC.x)+bfbits(aD.x);
      o4[1] = bfbits(aA.y)+bfbits(aB.y)+bfbits(aC.y)+bfbits(aD.y);
      o4[2] = bfbits(aA.z)+bfbits(aB.z)+bfbits(aC.z)+bfbits(aD.z);
      o4[3] = bfbits(aA.w)+bfbits(aB.w)+bfbits(aC.w)+bfbits(aD.w);
      float s = 0.f, ss = 0.f;
      #pragma unroll
      for (int e=0;e<4;e++){ s += o4[e]; ss += o4[e]*o4[e]; }
      s += __shfl_xor(s,1,64); ss += __shfl_xor(ss,1,64);
      s += __shfl_xor(s,2,64); ss += __shfl_xor(ss,2,64);
      s += __shfl_xor(s,4,64); ss += __shfl_xor(ss,4,64);
      s += __shfl_xor(s,8,64); ss += __shfl_xor(ss,8,64);
      s += __shfl_xor(s,16,64); ss += __shfl_xor(ss,16,64);
      float mu = s*(1.f/128.f);
      float inv = rsqrtf(fmaxf(ss*(1.f/128.f) - mu*mu, 0.f) + 1e-5f);
      float4 gw4 = *(const float4*)&gn_w[h*128+cq4];
      float4 gb4 = *(const float4*)&gn_b[h*128+cq4];
      size_t go = ((size_t)b*TT + tb + tq)*VD + h*128 + cq4;
      ushort4 g4 = *(const ushort4*)&((const unsigned short*)gg)[go];
      ushort4 out4;
      float xv, ga;
      xv = (o4[0]-mu)*inv*gw4.x + gb4.x; ga = bfbits(g4.x); xv *= ga/(1.f+expf(-ga)); out4.x = f2bfbits(xv);
      xv = (o4[1]-mu)*inv*gw4.y + gb4.y; ga = bfbits(g4.y); xv *= ga/(1.f+expf(-ga)); out4.y = f2bfbits(xv);
      xv = (o4[2]-mu)*inv*gw4.z + gb4.z; ga = bfbits(g4.z); xv *= ga/(1.f+expf(-ga)); out4.z = f2bfbits(xv);
      xv = (o4[3]-mu)*inv*gw4.w + gb4.w; ga = bfbits(g4.w); xv *= ga/(1.f+expf(-ga)); out4.w = f2bfbits(xv);
      *(ushort4*)&((unsigned short*)gated)[go] = out4;
    }
  }
}

extern "C" void kernel_launch(void* const* d_in, const int* in_sizes, int n_in,
                              void* d_out, int out_size, void* d_ws, size_t ws_size,
                              hipStream_t stream){
  (void)in_sizes; (void)n_in; (void)out_size;
  if (ws_size < WS_NEED) return;
  const float* x      = (const float*)d_in[0];
  const float* ln1w   = (const float*)d_in[1];
  const float* ln1b   = (const float*)d_in[2];
  const float* mu_x   = (const float*)d_in[3];
  const float* W_x1   = (const float*)d_in[4];
  const float* W_x2   = (const float*)d_in[5];
  const float* x_bias = (const float*)d_in[6];
  const float* W_r    = (const float*)d_in[7];
  const float* W_k    = (const float*)d_in[8];
  const float* W_v    = (const float*)d_in[9];
  const float* W_g    = (const float*)d_in[10];
  const float* W_w1   = (const float*)d_in[11];
  const float* W_w2   = (const float*)d_in[12];
  const float* b_w2   = (const float*)d_in[13];
  const float* u      = (const float*)d_in[14];
  const float* gn_w   = (const float*)d_in[15];
  const float* gn_b   = (const float*)d_in[16];
  const float* W_o    = (const float*)d_in[17];
  const float* ln2w   = (const float*)d_in[18];
  const float* ln2b   = (const float*)d_in[19];
  const float* mu_k   = (const float*)d_in[20];
  const float* W_key  = (const float*)d_in[21];
  const float* mu_r   = (const float*)d_in[22];
  const float* W_rec  = (const float*)d_in[23];
  const float* W_val  = (const float*)d_in[24];
  char* ws = (char*)d_ws;
  auto F  = [&](size_t off){ return (float*)(ws+off); };
  auto Bf = [&](size_t off){ return (bf16*)(ws+off); };
  float* h2 = (float*)d_out;        // attn-out residual lives in d_out
  bf16* Mseg = (bf16*)d_out;        // scan summaries alias d_out (dead before O-gemm)

  // weight conversions
  wconv_t2<<<620,256,0,stream>>>(W_x1,W_r,W_k,W_v,W_g,W_w1,W_w2,W_o,W_key,W_rec,W_val, ws);
  wconv_x2<<<320,256,0,stream>>>(W_x2, Bf(WT_X2T));

  // ---- attention pre-projections ----
  ln_xm<<<BT,256,0,stream>>>(x, ln1w, ln1b, mu_x, Bf(OFF_H1), Bf(OFF_HM));
  gemm12864<EP_TANH_BF16><<<1024,256,0,stream>>>(Bf(OFF_HM), Bf(WT_X1), Bf(OFF_XX), 256,512);

  // MFMA-fused 5-way hm build: hm0->HM, hm1->dout[0:32M], hm2->dout[32M:64M], hm3->G region, hm4->WD region
  bf16* hm1 = (bf16*)d_out;
  bf16* hm2 = (bf16*)((char*)d_out + 32*MiB);
  hm5_mfma<<<dim3(BT/128,4),256,0,stream>>>(Bf(OFF_H1), Bf(OFF_XX), Bf(WT_X2T), x_bias,
                                            Bf(OFF_HM), hm1, hm2, Bf(OFF_G), Bf(OFF_WD));
  // projections (order keeps region lifetimes disjoint)
  gemm12864<EP_BF16><<<1024,256,0,stream>>>(Bf(OFF_HM), Bf(WT_R), Bf(OFF_R), 256,512);
  gemm_bf16<EP_TANH_BF16><<<dim3(BT/128,1),256,0,stream>>>(hm1, Bf(WT_W1), Bf(OFF_W1T), 64,512, nullptr);
  gemm12864<EP_BF16><<<1024,256,0,stream>>>(hm2, Bf(WT_K), Bf(OFF_K), 256,512);
  gemm128<EP_BF16><<<1024,256,0,stream>>>(Bf(OFF_G), Bf(WT_V), Bf(OFF_V), 512,512, nullptr,nullptr);
  gemm128<EP_BF16><<<1024,256,0,stream>>>(Bf(OFF_WD), Bf(WT_G), Bf(OFF_G), 512,512, nullptr,nullptr);
  gemm_bf16<EP_NEGEXP_F16><<<dim3(BT/128,4),256,0,stream>>>(Bf(OFF_W1T), Bf(WT_W2), (void*)F(OFF_WD), 256,64, b_w2);

  // ---- WKV6 segment scan (SUB=64, NSUB=64); Mseg/Sstart in d_out ----
  wkv_p1<<<BB*4*NSUB,256,0,stream>>>(Bf(OFF_K), Bf(OFF_V), (const f16*)F(OFF_WD), Mseg, F(OFF_DSEG));
  wkv_p2<<<BB*4*8192/256,256,0,stream>>>(Mseg, F(OFF_DSEG));
  wkv_p3<<<BB*4*NSUB,256,0,stream>>>(Bf(OFF_R), Bf(OFF_K), Bf(OFF_V), (const f16*)F(OFF_WD), Mseg, u,
                                     Bf(OFF_G), gn_w, gn_b, Bf(OFF_H1));

  // ---- output projection + residual -> h2 (in d_out; overwrites Mseg) ----
  gemm128<EP_RES_F32><<<1024,256,0,stream>>>(Bf(OFF_H1), Bf(WT_O), h2, 512,512, x,nullptr);

  // ---- channel mixing (FFN); fused LN+lerp writes kin/rin directly ----
  ln_ffn<<<BT,256,0,stream>>>(h2, ln2w, ln2b, mu_k, mu_r, Bf(OFF_R), Bf(OFF_V));
  gemm128<EP_RELU2_BF16><<<2048,256,0,stream>>>(Bf(OFF_R), Bf(WT_KEY), Bf(OFF_WD), 1024,512, nullptr,nullptr);
  gemm128<EP_SIG_BF16><<<1024,256,0,stream>>>(Bf(OFF_V), Bf(WT_REC), Bf(OFF_H1), 512,512, nullptr,nullptr);
  gemm128<EP_FINAL_F32><<<1024,256,0,stream>>>(Bf(OFF_WD), Bf(WT_VAL), h2, 512,1024, h2, Bf(OFF_H1));
}

// Round 20
// 741.284 us; speedup vs baseline: 1.0199x; 1.0199x over previous
//
#include <hip/hip_runtime.h>
#include <hip/hip_bf16.h>
#include <hip/hip_fp16.h>
#include <math.h>

#define BB 8
#define TT 4096
#define CC 512
#define BT (BB*TT)
#define KD 256
#define VD 512
#define NSUB 64
#define SUB 64

using bf16 = __hip_bfloat16;
using f16 = _Float16;
typedef __attribute__((ext_vector_type(2))) float f32x2;
typedef __attribute__((ext_vector_type(4))) float f32x4;
typedef __attribute__((ext_vector_type(8))) short s16x8;
typedef __attribute__((ext_vector_type(8))) unsigned short u16x8;
typedef const __attribute__((address_space(1))) unsigned int gu32;
typedef __attribute__((address_space(3))) unsigned int lu32;

static __device__ __forceinline__ float bf2f(bf16 x){ return __bfloat162float(x); }
static __device__ __forceinline__ bf16 f2bf(float x){ return __float2bfloat16(x); }
static __device__ __forceinline__ float bfbits(unsigned short u){
  union { unsigned int i; float f; } x; x.i = ((unsigned int)u)<<16; return x.f;
}
static __device__ __forceinline__ unsigned short f2bfbits(float f){
  union { bf16 b; unsigned short u; } x; x.b = f2bf(f); return x.u;
}
static __device__ __forceinline__ float h2f(unsigned short u){
  f16 h; __builtin_memcpy(&h,&u,2); return (float)h;
}
static __device__ __forceinline__ void gload16(const void* g, void* l){
  __builtin_amdgcn_global_load_lds((gu32*)g, (lu32*)l, 16, 0, 0);
}

// ---------------- workspace arena (bytes); Mseg lives in d_out ----------------
#define MiB 1048576ull
static constexpr size_t OFF_H1   = 0;           // bf16 BT*C (32)  ; p3 out GATED ; FFN RF
static constexpr size_t OFF_XX   = 32*MiB;      // bf16 BT*256 (16); dead by scan
static constexpr size_t OFF_DSEG = 32*MiB;      // f32 2048*64 (0.5) alias XX
static constexpr size_t OFF_HM   = 48*MiB;      // bf16 BT*C (32) = xm, then hm0
static constexpr size_t OFF_R    = 80*MiB;      // bf16 BT*256 (16); FFN KIN (spans R+K)
static constexpr size_t OFF_K    = 96*MiB;      // bf16 BT*256 (16)
static constexpr size_t OFF_V    = 112*MiB;     // bf16 BT*512 (32); FFN RIN
static constexpr size_t OFF_WD   = 144*MiB;     // f16 BT*256 (16) ew; build: hm4 (32); FFN KF low
static constexpr size_t OFF_G    = 176*MiB;     // build: hm3 ; then g (32); FFN KF high
static constexpr size_t OFF_W1T  = 208*MiB;     // bf16 BT*64 (4)
static constexpr size_t WT_X1  = 212*MiB;            // 512x256 bf16
static constexpr size_t WT_R   = WT_X1  + 262144;
static constexpr size_t WT_K   = WT_R   + 262144;
static constexpr size_t WT_V   = WT_K   + 262144;
static constexpr size_t WT_G   = WT_V   + 524288;
static constexpr size_t WT_W1  = WT_G   + 524288;
static constexpr size_t WT_W2  = WT_W1  + 65536;
static constexpr size_t WT_O   = WT_W2  + 32768;
static constexpr size_t WT_KEY = WT_O   + 524288;
static constexpr size_t WT_REC = WT_KEY + 1048576;
static constexpr size_t WT_VAL = WT_REC + 524288;
static constexpr size_t WT_X2T = WT_VAL + 1048576;   // bf16 [5][512][32]
static constexpr size_t WS_NEED = WT_X2T + 163840;

// ---------------- tiled transposed weight convert (coalesced both sides) ----------------
__global__ __launch_bounds__(256) void wconv_t2(const float* s0, const float* s1, const float* s2,
        const float* s3, const float* s4, const float* s5, const float* s6, const float* s7,
        const float* s8, const float* s9, const float* s10, char* ws){
  struct E{int K,N,Npad; size_t off;};
  const E tab[11] = {
    {512,160,256,WT_X1},{512,256,256,WT_R},{512,256,256,WT_K},{512,512,512,WT_V},
    {512,512,512,WT_G},{512,64,64,WT_W1},{64,256,256,WT_W2},{512,512,512,WT_O},
    {512,1024,1024,WT_KEY},{512,512,512,WT_REC},{1024,512,512,WT_VAL}};
  const float* srcs[11] = {s0,s1,s2,s3,s4,s5,s6,s7,s8,s9,s10};
  int blk = blockIdx.x, i = 0, acc = 0;
  #pragma unroll 1
  for (; i<11; i++){ int nt = (tab[i].K>>6)*(tab[i].Npad>>6); if (blk < acc+nt) break; acc += nt; }
  int local = blk - acc;
  int K = tab[i].K, N = tab[i].N;
  int ntn = tab[i].Npad>>6;
  int k0 = (local/ntn)*64, n0 = (local%ntn)*64;
  const float* src = srcs[i];
  bf16* dst = (bf16*)(ws + tab[i].off);
  __shared__ float T[64][65];
  int t = threadIdx.x;
  #pragma unroll
  for (int e=0;e<16;e++){
    int idx = t + e*256; int r = idx>>6, c = idx&63;
    int n = n0 + c;
    T[r][c] = (n < N) ? src[(size_t)(k0+r)*N + n] : 0.f;
  }
  __syncthreads();
  #pragma unroll
  for (int e=0;e<16;e++){
    int idx = t + e*256; int r = idx>>6, c = idx&63;
    dst[(size_t)(n0+r)*K + k0 + c] = f2bf(T[c][r]);
  }
}

// ---------------- W_x2 -> bf16 [5][512][32] transposed (tiny) ----------------
__global__ void wconv_x2(const float* __restrict__ src, bf16* __restrict__ dst){
  int idx = blockIdx.x*256 + threadIdx.x;   // 81920 total
  int i = idx >> 14;
  int rem = idx & 16383;
  int c = rem >> 5, r = rem & 31;
  dst[idx] = f2bf(src[((size_t)i*32 + r)*512 + c]);
}

// ---------------- fused LN + token-shift lerp (attn): writes h1 AND xm ----------------
__global__ __launch_bounds__(256) void ln_xm(const float* __restrict__ x, const float* __restrict__ w,
        const float* __restrict__ b, const float* __restrict__ mu_x,
        bf16* __restrict__ h1, bf16* __restrict__ xm){
  int bt = blockIdx.x;
  bool hasp = (bt & (TT-1)) != 0;
  const float* row = x + (size_t)bt*CC;
  int t = threadIdx.x;
  float a0 = row[t], a1 = row[t+256];
  float p0 = 0.f, p1 = 0.f;
  if (hasp){ p0 = row[t-512]; p1 = row[t-256]; }
  float s = a0+a1, ss = a0*a0+a1*a1, sp = p0+p1, ssp = p0*p0+p1*p1;
  for (int off=32; off; off>>=1){
    s += __shfl_down(s,off,64); ss += __shfl_down(ss,off,64);
    sp += __shfl_down(sp,off,64); ssp += __shfl_down(ssp,off,64);
  }
  __shared__ float ps[4], pss[4], psp[4], pssp[4];
  int wv = t>>6, ln = t&63;
  if (ln==0){ ps[wv]=s; pss[wv]=ss; psp[wv]=sp; pssp[wv]=ssp; }
  __syncthreads();
  if (t==0){
    float S=ps[0]+ps[1]+ps[2]+ps[3], SS=pss[0]+pss[1]+pss[2]+pss[3];
    float SP=psp[0]+psp[1]+psp[2]+psp[3], SSP=pssp[0]+pssp[1]+pssp[2]+pssp[3];
    float mu = S/CC; float var = SS/CC - mu*mu;
    float mup = SP/CC; float varp = SSP/CC - mup*mup;
    ps[0]=mu; pss[0]=rsqrtf(var+1e-5f);
    psp[0]=mup; pssp[0]=rsqrtf(varp+1e-5f);
  }
  __syncthreads();
  float mu = ps[0], inv = pss[0], mup = psp[0], invp = pssp[0];
  float h0 = (a0-mu)*inv*w[t]+b[t];
  float h1v = (a1-mu)*inv*w[t+256]+b[t+256];
  float q0 = hasp ? (p0-mup)*invp*w[t]+b[t] : 0.f;
  float q1 = hasp ? (p1-mup)*invp*w[t+256]+b[t+256] : 0.f;
  size_t base = (size_t)bt*CC;
  h1[base+t]     = f2bf(h0);
  h1[base+t+256] = f2bf(h1v);
  xm[base+t]     = f2bf(h0 + (q0-h0)*mu_x[t]);
  xm[base+t+256] = f2bf(h1v + (q1-h1v)*mu_x[t+256]);
}

// ---------------- fused LN + FFN lerp: writes kin AND rin (hn eliminated) ----------------
__global__ __launch_bounds__(256) void ln_ffn(const float* __restrict__ x, const float* __restrict__ w,
        const float* __restrict__ b, const float* __restrict__ mu_k, const float* __restrict__ mu_r,
        bf16* __restrict__ kin, bf16* __restrict__ rin){
  int bt = blockIdx.x;
  bool hasp = (bt & (TT-1)) != 0;
  const float* row = x + (size_t)bt*CC;
  int t = threadIdx.x;
  float a0 = row[t], a1 = row[t+256];
  float p0 = 0.f, p1 = 0.f;
  if (hasp){ p0 = row[t-512]; p1 = row[t-256]; }
  float s = a0+a1, ss = a0*a0+a1*a1, sp = p0+p1, ssp = p0*p0+p1*p1;
  for (int off=32; off; off>>=1){
    s += __shfl_down(s,off,64); ss += __shfl_down(ss,off,64);
    sp += __shfl_down(sp,off,64); ssp += __shfl_down(ssp,off,64);
  }
  __shared__ float ps[4], pss[4], psp[4], pssp[4];
  int wv = t>>6, ln = t&63;
  if (ln==0){ ps[wv]=s; pss[wv]=ss; psp[wv]=sp; pssp[wv]=ssp; }
  __syncthreads();
  if (t==0){
    float S=ps[0]+ps[1]+ps[2]+ps[3], SS=pss[0]+pss[1]+pss[2]+pss[3];
    float SP=psp[0]+psp[1]+psp[2]+psp[3], SSP=pssp[0]+pssp[1]+pssp[2]+pssp[3];
    float mu = S/CC; float var = SS/CC - mu*mu;
    float mup = SP/CC; float varp = SSP/CC - mup*mup;
    ps[0]=mu; pss[0]=rsqrtf(var+1e-5f);
    psp[0]=mup; pssp[0]=rsqrtf(varp+1e-5f);
  }
  __syncthreads();
  float mu = ps[0], inv = pss[0], mup = psp[0], invp = pssp[0];
  float h0 = (a0-mu)*inv*w[t]+b[t];
  float h1v = (a1-mu)*inv*w[t+256]+b[t+256];
  float q0 = hasp ? (p0-mup)*invp*w[t]+b[t] : 0.f;
  float q1 = hasp ? (p1-mup)*invp*w[t+256]+b[t+256] : 0.f;
  float d0 = q0-h0, d1 = q1-h1v;
  size_t base = (size_t)bt*CC;
  kin[base+t]     = f2bf(h0 + d0*mu_k[t]);
  kin[base+t+256] = f2bf(h1v + d1*mu_k[t+256]);
  rin[base+t]     = f2bf(h0 + d0*mu_r[t]);
  rin[base+t+256] = f2bf(h1v + d1*mu_r[t+256]);
}

// ---------------- MFMA-fused 5-way lerp-mix build ----------------
__global__ __launch_bounds__(256) void hm5_mfma(const bf16* __restrict__ h, const bf16* __restrict__ xx,
      const bf16* __restrict__ wx2t, const float* __restrict__ x_bias,
      bf16* __restrict__ hm0, bf16* __restrict__ hm1, bf16* __restrict__ hm2,
      bf16* __restrict__ hm3, bf16* __restrict__ hm4){
  __shared__ bf16 xxl[128][168];
  int bt0 = blockIdx.x*128;
  int c0 = blockIdx.y*128;
  int tid = threadIdx.x;
  #pragma unroll
  for (int p=0;p<10;p++){
    int idx = p*256 + tid;
    int row = idx/20, q = idx - row*20;
    *(uint4*)&xxl[row][q*8] = *(const uint4*)&xx[((size_t)(bt0+row))*256 + q*8];
  }
  __syncthreads();
  int wv = tid>>6, ln = tid&63;
  int wr = wv>>1, wc = wv&1;
  int ks = (ln>>4)*8;
  int l15 = ln&15;
  bf16* const outs[5] = {hm0,hm1,hm2,hm3,hm4};
  #pragma unroll
  for (int i=0;i<5;i++){
    s16x8 bq[4];
    #pragma unroll
    for (int ni=0;ni<4;ni++)
      bq[ni] = *(const s16x8*)&xxl[wc*64 + ni*16 + l15][i*32 + ks];
    f32x4 acc[4][4];
    #pragma unroll
    for (int mi=0;mi<4;mi++){
      int chb = c0 + wr*64 + mi*16 + (ln>>4)*4;
      float4 bia = *(const float4*)&x_bias[i*CC + chb];
      #pragma unroll
      for (int ni=0;ni<4;ni++){ f32x4 a = {bia.x,bia.y,bia.z,bia.w}; acc[mi][ni] = a; }
    }
    #pragma unroll
    for (int mi=0;mi<4;mi++){
      s16x8 aw = *(const s16x8*)&wx2t[((size_t)i*512 + c0 + wr*64 + mi*16 + l15)*32 + ks];
      #pragma unroll
      for (int ni=0;ni<4;ni++)
        acc[mi][ni] = __builtin_amdgcn_mfma_f32_16x16x32_bf16(aw, bq[ni], acc[mi][ni], 0,0,0);
    }
    bf16* o = outs[i];
    #pragma unroll
    for (int mi=0;mi<4;mi++){
      int ch = c0 + wr*64 + mi*16 + (ln>>4)*4;
      #pragma unroll
      for (int ni=0;ni<4;ni++){
        int tok = bt0 + wc*64 + ni*16 + l15;
        size_t base = (size_t)tok*CC + ch;
        ushort4 hv4 = *(const ushort4*)&((const unsigned short*)h)[base];
        ushort4 hp4;
        if (tok & (TT-1)) hp4 = *(const ushort4*)&((const unsigned short*)h)[base - CC];
        else { hp4.x=0; hp4.y=0; hp4.z=0; hp4.w=0; }
        ushort4 o4;
        float hv, hp, mus;
        hv = bfbits(hv4.x); hp = bfbits(hp4.x); mus = acc[mi][ni][0]; o4.x = f2bfbits(hv + (hp-hv)*mus);
        hv = bfbits(hv4.y); hp = bfbits(hp4.y); mus = acc[mi][ni][1]; o4.y = f2bfbits(hv + (hp-hv)*mus);
        hv = bfbits(hv4.z); hp = bfbits(hp4.z); mus = acc[mi][ni][2]; o4.z = f2bfbits(hv + (hp-hv)*mus);
        hv = bfbits(hv4.w); hp = bfbits(hp4.w); mus = acc[mi][ni][3]; o4.w = f2bfbits(hv + (hp-hv)*mus);
        *(ushort4*)&((unsigned short*)o)[base] = o4;
      }
    }
  }
}

// ---------------- epilogue modes ----------------
enum {EP_BF16, EP_TANH_BF16, EP_NEGEXP_F16, EP_RES_F32, EP_RELU2_BF16, EP_SIG_BF16, EP_FINAL_F32};

// ---------------- 128x128 MFMA GEMM, BK=64, XOR-swizzled LDS (linear dest + pre-swz src) ----
template<int MODE>
__global__ __launch_bounds__(256) void gemm128(
    const bf16* __restrict__ A, const bf16* __restrict__ Bt, void* __restrict__ Out,
    int N, int K, const float* __restrict__ auxf, const bf16* __restrict__ auxb)
{
  __shared__ bf16 Al[128][64];
  __shared__ bf16 Bl[128][64];
  int tid = threadIdx.x;
  int nbk = N>>7;
  int q8 = gridDim.x>>3;
  int o = (blockIdx.x & 7)*q8 + (blockIdx.x>>3);
  int nb = o % nbk, mb = o / nbk;
  int m0 = mb*128, n0 = nb*128;
  int wv = tid>>6, ln = tid&63;
  int wr = wv>>1, wc = wv&1;
  f32x4 acc[4][4];
  #pragma unroll
  for (int i=0;i<4;i++) for (int j=0;j<4;j++){ f32x4 z={0.f,0.f,0.f,0.f}; acc[i][j]=z; }
  int r0 = tid>>3;
  int sl = (tid&7) ^ (r0&7);
  int l15 = ln&15, lswz = l15&7;
  const int nkt = K>>6;
  for (int kt=0; kt<nkt; kt++){
    const bf16* ga = A  + (size_t)(m0+r0)*K + kt*64 + sl*8;
    const bf16* gb = Bt + (size_t)(n0+r0)*K + kt*64 + sl*8;
    #pragma unroll
    for (int j=0;j<4;j++){
      gload16(ga + (size_t)(j*32)*K, (char*)&Al[0][0] + (tid + j*256)*16);
      gload16(gb + (size_t)(j*32)*K, (char*)&Bl[0][0] + (tid + j*256)*16);
    }
    __syncthreads();
    #pragma unroll
    for (int kh=0; kh<2; kh++){
      int slot = (kh*4 + (ln>>4)) ^ lswz;
      s16x8 af[4], bq[4];
      #pragma unroll
      for (int i=0;i<4;i++){
        int ra = wr*64 + i*16 + l15;
        int rb2 = wc*64 + i*16 + l15;
        af[i] = *(const s16x8*)((const char*)&Al[0][0] + ra*128 + slot*16);
        bq[i] = *(const s16x8*)((const char*)&Bl[0][0] + rb2*128 + slot*16);
      }
      #pragma unroll
      for (int mi=0;mi<4;mi++)
        #pragma unroll
        for (int ni=0;ni<4;ni++)
          acc[mi][ni] = __builtin_amdgcn_mfma_f32_16x16x32_bf16(af[mi], bq[ni], acc[mi][ni], 0,0,0);
    }
    __syncthreads();
  }
  #pragma unroll
  for (int mi=0;mi<4;mi++)
    #pragma unroll
    for (int ni=0;ni<4;ni++){
      int col = n0 + wc*64 + ni*16 + (ln&15);
      int rb  = m0 + wr*64 + mi*16 + (ln>>4)*4;
      #pragma unroll
      for (int j=0;j<4;j++){
        size_t idx = (size_t)(rb+j)*N + col;
        float val = acc[mi][ni][j];
        if constexpr(MODE==EP_BF16)           ((bf16*)Out)[idx] = f2bf(val);
        else if constexpr(MODE==EP_TANH_BF16) ((bf16*)Out)[idx] = f2bf(tanhf(val));
        else if constexpr(MODE==EP_RES_F32)   ((float*)Out)[idx] = auxf[idx] + val;
        else if constexpr(MODE==EP_RELU2_BF16){ float m = fmaxf(val,0.f); ((bf16*)Out)[idx] = f2bf(m*m); }
        else if constexpr(MODE==EP_SIG_BF16)  ((bf16*)Out)[idx] = f2bf(1.f/(1.f+expf(-val)));
        else if constexpr(MODE==EP_FINAL_F32) ((float*)Out)[idx] = auxf[idx] + bf2f(auxb[idx])*val;
      }
    }
}

// ---------------- 128x64-tile GEMM, BK=64, same swizzle (N=256 outputs) -------------
template<int MODE>
__global__ __launch_bounds__(256) void gemm12864(
    const bf16* __restrict__ A, const bf16* __restrict__ Bt, void* __restrict__ Out,
    int N, int K)
{
  __shared__ bf16 Al[128][64];
  __shared__ bf16 Bl[64][64];
  int tid = threadIdx.x;
  int nbk = N>>6;
  int q8 = gridDim.x>>3;
  int o = (blockIdx.x & 7)*q8 + (blockIdx.x>>3);
  int nb = o % nbk, mb = o / nbk;
  int m0 = mb*128, n0 = nb*64;
  int wv = tid>>6, ln = tid&63;
  int wr = wv>>1, wc = wv&1;
  f32x4 acc[4][2];
  #pragma unroll
  for (int i=0;i<4;i++) for (int j=0;j<2;j++){ f32x4 z={0.f,0.f,0.f,0.f}; acc[i][j]=z; }
  int r0 = tid>>3;
  int sl = (tid&7) ^ (r0&7);
  int l15 = ln&15, lswz = l15&7;
  const int nkt = K>>6;
  for (int kt=0; kt<nkt; kt++){
    const bf16* ga = A  + (size_t)(m0+r0)*K + kt*64 + sl*8;
    const bf16* gb = Bt + (size_t)(n0+r0)*K + kt*64 + sl*8;
    #pragma unroll
    for (int j=0;j<4;j++)
      gload16(ga + (size_t)(j*32)*K, (char*)&Al[0][0] + (tid + j*256)*16);
    #pragma unroll
    for (int j=0;j<2;j++)
      gload16(gb + (size_t)(j*32)*K, (char*)&Bl[0][0] + (tid + j*256)*16);
    __syncthreads();
    #pragma unroll
    for (int kh=0; kh<2; kh++){
      int slot = (kh*4 + (ln>>4)) ^ lswz;
      s16x8 af[4], bq[2];
      #pragma unroll
      for (int i=0;i<4;i++){
        int ra = wr*64 + i*16 + l15;
        af[i] = *(const s16x8*)((const char*)&Al[0][0] + ra*128 + slot*16);
      }
      #pragma unroll
      for (int i=0;i<2;i++){
        int rb2 = wc*32 + i*16 + l15;
        bq[i] = *(const s16x8*)((const char*)&Bl[0][0] + rb2*128 + slot*16);
      }
      #pragma unroll
      for (int mi=0;mi<4;mi++)
        #pragma unroll
        for (int ni=0;ni<2;ni++)
          acc[mi][ni] = __builtin_amdgcn_mfma_f32_16x16x32_bf16(af[mi], bq[ni], acc[mi][ni], 0,0,0);
    }
    __syncthreads();
  }
  #pragma unroll
  for (int mi=0;mi<4;mi++)
    #pragma unroll
    for (int ni=0;ni<2;ni++){
      int col = n0 + wc*32 + ni*16 + (ln&15);
      int rb  = m0 + wr*64 + mi*16 + (ln>>4)*4;
      #pragma unroll
      for (int j=0;j<4;j++){
        size_t idx = (size_t)(rb+j)*N + col;
        float val = acc[mi][ni][j];
        if constexpr(MODE==EP_BF16)           ((bf16*)Out)[idx] = f2bf(val);
        else if constexpr(MODE==EP_TANH_BF16) ((bf16*)Out)[idx] = f2bf(tanhf(val));
      }
    }
}

// ---------------- small-N GEMM (used for W1 N=64 and W2 K=64) -------------
template<int MODE>
__global__ __launch_bounds__(256) void gemm_bf16(
    const bf16* __restrict__ A, const bf16* __restrict__ Bt, void* __restrict__ Out,
    int N, int K, const float* __restrict__ bias)
{
  __shared__ bf16 Al[128][40];
  __shared__ bf16 Bl[64][40];
  int tid = threadIdx.x;
  int m0 = blockIdx.x*128, n0 = blockIdx.y*64;
  int wv = tid>>6, ln = tid&63;
  f32x4 acc[2][4];
  #pragma unroll
  for(int f=0;f<2;f++) for(int c=0;c<4;c++){ f32x4 z = {0.f,0.f,0.f,0.f}; acc[f][c]=z; }
  const int nkt = K>>5;
  for (int kt=0; kt<nkt; kt++){
    __syncthreads();
    {
      int c0 = tid, c1 = tid+256;
      int r = c0>>2, ko=(c0&3)*8;
      *(uint4*)&Al[r][ko] = *(const uint4*)&A[(size_t)(m0+r)*K + kt*32 + ko];
      r = c1>>2; ko=(c1&3)*8;
      *(uint4*)&Al[r][ko] = *(const uint4*)&A[(size_t)(m0+r)*K + kt*32 + ko];
      r = tid>>2; ko=(tid&3)*8;
      *(uint4*)&Bl[r][ko] = *(const uint4*)&Bt[(size_t)(n0+r)*K + kt*32 + ko];
    }
    __syncthreads();
    int ks = (ln>>4)*8;
    s16x8 af0 = *(const s16x8*)&Al[wv*32 + (ln&15)][ks];
    s16x8 af1 = *(const s16x8*)&Al[wv*32 + 16 + (ln&15)][ks];
    #pragma unroll
    for (int c=0;c<4;c++){
      s16x8 bfr = *(const s16x8*)&Bl[c*16 + (ln&15)][ks];
      acc[0][c] = __builtin_amdgcn_mfma_f32_16x16x32_bf16(af0, bfr, acc[0][c], 0,0,0);
      acc[1][c] = __builtin_amdgcn_mfma_f32_16x16x32_bf16(af1, bfr, acc[1][c], 0,0,0);
    }
  }
  #pragma unroll
  for (int f=0; f<2; f++) for (int c=0;c<4;c++){
    int col = n0 + c*16 + (ln&15);
    int rbase = m0 + wv*32 + f*16 + (ln>>4)*4;
    #pragma unroll
    for (int j=0;j<4;j++){
      size_t idx = (size_t)(rbase+j)*N + col;
      float val = acc[f][c][j];
      if constexpr(MODE==EP_TANH_BF16)      ((bf16*)Out)[idx] = f2bf(tanhf(val));
      else if constexpr(MODE==EP_NEGEXP_F16){
        float w = fmaxf(-expf(val + bias[col]), -20.f);
        ((f16*)Out)[idx] = (f16)expf(w);
      }
    }
  }
}

// ---------------- WKV6 segment scan (64-token chunks, NSUB=64) ----------------
// P1: 256 threads; thread = (k-lane, v-quarter). ew/k staged coalescedly into LDS per 16-token tile.
__global__ __launch_bounds__(256) void wkv_p1(const bf16* __restrict__ kbuf, const bf16* __restrict__ vbuf,
      const f16* __restrict__ ewb, bf16* __restrict__ Mseg, float* __restrict__ Dseg){
  int bhs = blockIdx.x; int bh = bhs>>6, sub = bhs&63;
  int b = bh>>2, h = bh&3;
  int tid = threadIdx.x, ln = tid&63, vq = tid>>6;
  __shared__ float vtile[16][132];
  __shared__ float ew16[16][66];
  __shared__ float qk16[16][66];
  int t0 = sub*SUB;
  float dacc = 1.f;
  f32x2 S2[16];
  #pragma unroll
  for (int p=0;p<16;p++){ f32x2 z={0.f,0.f}; S2[p]=z; }
  #pragma unroll 1
  for (int tile=0; tile<4; tile++){
    int tb = t0 + tile*16;
    __syncthreads();
    {
      int t = tid>>4, c = (tid&15)*8;
      u16x8 a8 = *(const u16x8*)&((const unsigned short*)vbuf)[((size_t)b*TT + tb + t)*VD + h*128 + c];
      float4 lo, hi;
      lo.x=bfbits(a8[0]); lo.y=bfbits(a8[1]); lo.z=bfbits(a8[2]); lo.w=bfbits(a8[3]);
      hi.x=bfbits(a8[4]); hi.y=bfbits(a8[5]); hi.z=bfbits(a8[6]); hi.w=bfbits(a8[7]);
      *(float4*)&vtile[t][c]   = lo;
      *(float4*)&vtile[t][c+4] = hi;
    }
    #pragma unroll
    for (int j=0;j<2;j++){
      int idx = j*512 + tid*2;
      int t = idx>>6, c = idx&63;
      size_t gi = ((size_t)b*TT + tb + t)*KD + h*64 + c;
      ushort2 e2 = *(const ushort2*)&((const unsigned short*)ewb)[gi];
      ushort2 k2 = *(const ushort2*)&((const unsigned short*)kbuf)[gi];
      ew16[t][c] = h2f(e2.x);   ew16[t][c+1] = h2f(e2.y);
      qk16[t][c] = bfbits(k2.x); qk16[t][c+1] = bfbits(k2.y);
    }
    __syncthreads();
    #pragma unroll 2
    for (int tt=0;tt<16;tt++){
      float e = ew16[tt][ln];
      float qv = qk16[tt][ln];
      dacc *= e;
      f32x2 e2v = {e,e}, q2 = {qv,qv};
      #pragma unroll
      for (int vg=0;vg<8;vg++){
        f32x4 vvv = *(const f32x4*)&vtile[tt][vq*32 + vg*4];
        f32x2 vA = {vvv[0], vvv[1]}, vB = {vvv[2], vvv[3]};
        S2[vg*2]   = e2v*S2[vg*2]   + q2*vA;
        S2[vg*2+1] = e2v*S2[vg*2+1] + q2*vB;
      }
    }
  }
  unsigned short* M = (unsigned short*)Mseg + (size_t)bhs*8192 + (size_t)ln*128 + vq*32;
  #pragma unroll
  for (int vg=0; vg<8; vg++){
    ushort4 s4;
    s4.x = f2bfbits(S2[vg*2][0]);   s4.y = f2bfbits(S2[vg*2][1]);
    s4.z = f2bfbits(S2[vg*2+1][0]); s4.w = f2bfbits(S2[vg*2+1][1]);
    *(ushort4*)&M[vg*4] = s4;
  }
  if (vq==0) Dseg[(size_t)bhs*64 + ln] = dacc;
}

// P2: sequential combine across sub-chunks, IN-PLACE bf16 (Mseg becomes Sstart)
__global__ __launch_bounds__(256) void wkv_p2(bf16* __restrict__ MS, const float* __restrict__ Dseg){
  int idx = blockIdx.x*256 + threadIdx.x;
  int bh = idx>>13; int k = (idx>>7)&63; int v = idx&127;
  bf16* p = MS + (size_t)bh*NSUB*8192 + k*128 + v;
  const float* d = Dseg + (size_t)bh*NSUB*64 + k;
  float S = 0.f;
  float m = bf2f(p[0]); float D = d[0];
  #pragma unroll 1
  for (int seg=0; seg<NSUB; seg++){
    float mN=0.f, DN=0.f;
    if (seg < NSUB-1){ mN = bf2f(p[(size_t)(seg+1)*8192]); DN = d[(seg+1)*64]; }
    p[(size_t)seg*8192] = f2bf(S);
    S = D*S + m;
    m = mN; D = DN;
  }
}

// P3: 256 threads; thread = (k-QUARTER, 2 v-channels). State S2[16] = 16 k x f32x2(2 channels).
// 2 barriers/tile: end-of-tile barrier removed (next stage-write doesn't touch otp/GN inputs;
// next compute's otp writes are fenced by the post-stage barrier).
__global__ __launch_bounds__(256) void wkv_p3(const bf16* __restrict__ rbuf, const bf16* __restrict__ kbuf,
     const bf16* __restrict__ vbuf, const f16* __restrict__ ewb, const bf16* __restrict__ Sstart,
     const float* __restrict__ uu, const bf16* __restrict__ gg,
     const float* __restrict__ gn_w, const float* __restrict__ gn_b, bf16* __restrict__ gated){
  int bhs = blockIdx.x; int bh = bhs>>6, sub = bhs&63;
  int b = bh>>2, h = bh&3;
  int tid = threadIdx.x;
  __shared__ float ew[8][68], qk[8][68], rr[8][68], bu[8];
  __shared__ unsigned short vtb[8][128];
  __shared__ float otp[4][8][132];
  int v0 = tid&63, kq = tid>>6, kbase = kq*16;
  int tq = tid>>5, c2 = (tid&31)*2, cq4 = (tid&31)*4;
  float2 u2 = *(const float2*)&uu[h*64 + c2];
  f32x2 S2[16];   // S2[p] = { S[kbase+p][v0], S[kbase+p][v0+64] }
  const unsigned short* Sst = (const unsigned short*)Sstart + (size_t)bhs*8192;
  #pragma unroll
  for (int p=0;p<16;p++){
    f32x2 s = { bfbits(Sst[(kbase+p)*128 + v0]), bfbits(Sst[(kbase+p)*128 + v0 + 64]) };
    S2[p] = s;
  }
  int t0 = sub*SUB;
  ushort2 nE, nK, nR; ushort4 nV;
  auto loadt = [&](int tile){
    int tb = t0 + tile*8;
    size_t gi = ((size_t)b*TT + tb + tq)*KD + h*64 + c2;
    nE = *(const ushort2*)&((const unsigned short*)ewb)[gi];
    nK = *(const ushort2*)&((const unsigned short*)kbuf)[gi];
    nR = *(const ushort2*)&((const unsigned short*)rbuf)[gi];
    nV = *(const ushort4*)&((const unsigned short*)vbuf)[((size_t)b*TT + tb + tq)*VD + h*128 + cq4];
  };
  loadt(0);
  #pragma unroll 1
  for (int tile=0; tile<8; tile++){
    int tb = t0 + tile*8;
    {
      ew[tq][c2] = h2f(nE.x); ew[tq][c2+1] = h2f(nE.y);
      float q0=bfbits(nK.x), q1=bfbits(nK.y);
      float rv0=bfbits(nR.x), rv1=bfbits(nR.y);
      qk[tq][c2]=q0; qk[tq][c2+1]=q1;
      rr[tq][c2]=rv0; rr[tq][c2+1]=rv1;
      float part = rv0*q0*u2.x + rv1*q1*u2.y;
      part += __shfl_xor(part,1,64); part += __shfl_xor(part,2,64);
      part += __shfl_xor(part,4,64); part += __shfl_xor(part,8,64);
      part += __shfl_xor(part,16,64);
      if ((tid&31)==0) bu[tq] = part;
      *(ushort4*)&vtb[tq][cq4] = nV;
    }
    __syncthreads();
    if (tile < 7) loadt(tile+1);
    #pragma unroll 1
    for (int t=0;t<8;t++){
      f32x2 vl2 = { bfbits(vtb[t][v0]), bfbits(vtb[t][v0+64]) };
      f32x2 o2 = {0.f, 0.f};
      #pragma unroll
      for (int g=0;g<4;g++){
        f32x4 e4 = *(const f32x4*)&ew[t][kbase + g*4];
        f32x4 q4 = *(const f32x4*)&qk[t][kbase + g*4];
        f32x4 r4 = *(const f32x4*)&rr[t][kbase + g*4];
        int p = g*4;
        f32x2 e0={e4[0],e4[0]}, q0={q4[0],q4[0]}, r0={r4[0],r4[0]};
        f32x2 e1={e4[1],e4[1]}, q1={q4[1],q4[1]}, r1={r4[1],r4[1]};
        f32x2 e2={e4[2],e4[2]}, q2={q4[2],q4[2]}, r2={r4[2],r4[2]};
        f32x2 e3={e4[3],e4[3]}, q3={q4[3],q4[3]}, r3={r4[3],r4[3]};
        o2 += r0*S2[p+0]; S2[p+0] = e0*S2[p+0] + q0*vl2;
        o2 += r1*S2[p+1]; S2[p+1] = e1*S2[p+1] + q1*vl2;
        o2 += r2*S2[p+2]; S2[p+2] = e2*S2[p+2] + q2*vl2;
        o2 += r3*S2[p+3]; S2[p+3] = e3*S2[p+3] + q3*vl2;
      }
      if (kq==0){ float bb = bu[t]; o2[0] += bb*vl2[0]; o2[1] += bb*vl2[1]; }
      otp[kq][t][v0]      = o2[0];
      otp[kq][t][v0 + 64] = o2[1];
    }
    __syncthreads();
    {
      float4 oA = *(const float4*)&otp[0][tq][cq4];
      float4 oB = *(const float4*)&otp[1][tq][cq4];
      float4 oC = *(const float4*)&otp[2][tq][cq4];
      float4 oD = *(const float4*)&otp[3][tq][cq4];
      float o4[4] = {oA.x+oB.x+oC.x+oD.x, oA.y+oB.y+oC.y+oD.y,
                     oA.z+oB.z+oC.z+oD.z, oA.w+oB.w+oC.w+oD.w};
      float s = 0.f, ss = 0.f;
      #pragma unroll
      for (int e=0;e<4;e++){ s += o4[e]; ss += o4[e]*o4[e]; }
      s += __shfl_xor(s,1,64); ss += __shfl_xor(ss,1,64);
      s += __shfl_xor(s,2,64); ss += __shfl_xor(ss,2,64);
      s += __shfl_xor(s,4,64); ss += __shfl_xor(ss,4,64);
      s += __shfl_xor(s,8,64); ss += __shfl_xor(ss,8,64);
      s += __shfl_xor(s,16,64); ss += __shfl_xor(ss,16,64);
      float mu = s*(1.f/128.f);
      float inv = rsqrtf(fmaxf(ss*(1.f/128.f) - mu*mu, 0.f) + 1e-5f);
      float4 gw4 = *(const float4*)&gn_w[h*128+cq4];
      float4 gb4 = *(const float4*)&gn_b[h*128+cq4];
      size_t go = ((size_t)b*TT + tb + tq)*VD + h*128 + cq4;
      ushort4 g4 = *(const ushort4*)&((const unsigned short*)gg)[go];
      ushort4 out4;
      float xv, ga;
      xv = (o4[0]-mu)*inv*gw4.x + gb4.x; ga = bfbits(g4.x); xv *= ga/(1.f+expf(-ga)); out4.x = f2bfbits(xv);
      xv = (o4[1]-mu)*inv*gw4.y + gb4.y; ga = bfbits(g4.y); xv *= ga/(1.f+expf(-ga)); out4.y = f2bfbits(xv);
      xv = (o4[2]-mu)*inv*gw4.z + gb4.z; ga = bfbits(g4.z); xv *= ga/(1.f+expf(-ga)); out4.z = f2bfbits(xv);
      xv = (o4[3]-mu)*inv*gw4.w + gb4.w; ga = bfbits(g4.w); xv *= ga/(1.f+expf(-ga)); out4.w = f2bfbits(xv);
      *(ushort4*)&((unsigned short*)gated)[go] = out4;
    }
    // end-of-tile barrier removed: next stage-write (ew/qk/rr/vtb/bu) is safe — all compute
    // reads were fenced by the post-compute barrier; next otp writes are fenced by post-stage barrier.
  }
}

extern "C" void kernel_launch(void* const* d_in, const int* in_sizes, int n_in,
                              void* d_out, int out_size, void* d_ws, size_t ws_size,
                              hipStream_t stream){
  (void)in_sizes; (void)n_in; (void)out_size;
  if (ws_size < WS_NEED) return;
  const float* x      = (const float*)d_in[0];
  const float* ln1w   = (const float*)d_in[1];
  const float* ln1b   = (const float*)d_in[2];
  const float* mu_x   = (const float*)d_in[3];
  const float* W_x1   = (const float*)d_in[4];
  const float* W_x2   = (const float*)d_in[5];
  const float* x_bias = (const float*)d_in[6];
  const float* W_r    = (const float*)d_in[7];
  const float* W_k    = (const float*)d_in[8];
  const float* W_v    = (const float*)d_in[9];
  const float* W_g    = (const float*)d_in[10];
  const float* W_w1   = (const float*)d_in[11];
  const float* W_w2   = (const float*)d_in[12];
  const float* b_w2   = (const float*)d_in[13];
  const float* u      = (const float*)d_in[14];
  const float* gn_w   = (const float*)d_in[15];
  const float* gn_b   = (const float*)d_in[16];
  const float* W_o    = (const float*)d_in[17];
  const float* ln2w   = (const float*)d_in[18];
  const float* ln2b   = (const float*)d_in[19];
  const float* mu_k   = (const float*)d_in[20];
  const float* W_key  = (const float*)d_in[21];
  const float* mu_r   = (const float*)d_in[22];
  const float* W_rec  = (const float*)d_in[23];
  const float* W_val  = (const float*)d_in[24];
  char* ws = (char*)d_ws;
  auto F  = [&](size_t off){ return (float*)(ws+off); };
  auto Bf = [&](size_t off){ return (bf16*)(ws+off); };
  float* h2 = (float*)d_out;        // attn-out residual lives in d_out
  bf16* Mseg = (bf16*)d_out;        // scan summaries alias d_out (dead before O-gemm)

  // weight conversions
  wconv_t2<<<620,256,0,stream>>>(W_x1,W_r,W_k,W_v,W_g,W_w1,W_w2,W_o,W_key,W_rec,W_val, ws);
  wconv_x2<<<320,256,0,stream>>>(W_x2, Bf(WT_X2T));

  // ---- attention pre-projections ----
  ln_xm<<<BT,256,0,stream>>>(x, ln1w, ln1b, mu_x, Bf(OFF_H1), Bf(OFF_HM));
  gemm12864<EP_TANH_BF16><<<1024,256,0,stream>>>(Bf(OFF_HM), Bf(WT_X1), Bf(OFF_XX), 256,512);

  // MFMA-fused 5-way hm build: hm0->HM, hm1->dout[0:32M], hm2->dout[32M:64M], hm3->G region, hm4->WD region
  bf16* hm1 = (bf16*)d_out;
  bf16* hm2 = (bf16*)((char*)d_out + 32*MiB);
  hm5_mfma<<<dim3(BT/128,4),256,0,stream>>>(Bf(OFF_H1), Bf(OFF_XX), Bf(WT_X2T), x_bias,
                                            Bf(OFF_HM), hm1, hm2, Bf(OFF_G), Bf(OFF_WD));
  // projections (order keeps region lifetimes disjoint)
  gemm12864<EP_BF16><<<1024,256,0,stream>>>(Bf(OFF_HM), Bf(WT_R), Bf(OFF_R), 256,512);
  gemm_bf16<EP_TANH_BF16><<<dim3(BT/128,1),256,0,stream>>>(hm1, Bf(WT_W1), Bf(OFF_W1T), 64,512, nullptr);
  gemm12864<EP_BF16><<<1024,256,0,stream>>>(hm2, Bf(WT_K), Bf(OFF_K), 256,512);
  gemm128<EP_BF16><<<1024,256,0,stream>>>(Bf(OFF_G), Bf(WT_V), Bf(OFF_V), 512,512, nullptr,nullptr);
  gemm128<EP_BF16><<<1024,256,0,stream>>>(Bf(OFF_WD), Bf(WT_G), Bf(OFF_G), 512,512, nullptr,nullptr);
  gemm_bf16<EP_NEGEXP_F16><<<dim3(BT/128,4),256,0,stream>>>(Bf(OFF_W1T), Bf(WT_W2), (void*)F(OFF_WD), 256,64, b_w2);

  // ---- WKV6 segment scan (SUB=64, NSUB=64); Mseg/Sstart in d_out ----
  wkv_p1<<<BB*4*NSUB,256,0,stream>>>(Bf(OFF_K), Bf(OFF_V), (const f16*)F(OFF_WD), Mseg, F(OFF_DSEG));
  wkv_p2<<<BB*4*8192/256,256,0,stream>>>(Mseg, F(OFF_DSEG));
  wkv_p3<<<BB*4*NSUB,256,0,stream>>>(Bf(OFF_R), Bf(OFF_K), Bf(OFF_V), (const f16*)F(OFF_WD), Mseg, u,
                                     Bf(OFF_G), gn_w, gn_b, Bf(OFF_H1));

  // ---- output projection + residual -> h2 (in d_out; overwrites Mseg) ----
  gemm128<EP_RES_F32><<<1024,256,0,stream>>>(Bf(OFF_H1), Bf(WT_O), h2, 512,512, x,nullptr);

  // ---- channel mixing (FFN); fused LN+lerp writes kin/rin directly ----
  ln_ffn<<<BT,256,0,stream>>>(h2, ln2w, ln2b, mu_k, mu_r, Bf(OFF_R), Bf(OFF_V));
  gemm128<EP_RELU2_BF16><<<2048,256,0,stream>>>(Bf(OFF_R), Bf(WT_KEY), Bf(OFF_WD), 1024,512, nullptr,nullptr);
  gemm128<EP_SIG_BF16><<<1024,256,0,stream>>>(Bf(OFF_V), Bf(WT_REC), Bf(OFF_H1), 512,512, nullptr,nullptr);
  gemm128<EP_FINAL_F32><<<1024,256,0,stream>>>(Bf(OFF_WD), Bf(WT_VAL), h2, 512,1024, h2, Bf(OFF_H1));
}